// Round 7
// baseline (224.294 us; speedup 1.0000x reference)
//
#include <hip/hip_runtime.h>
#include <hip/hip_bf16.h>

// Problem constants
#define Bc 8
#define Tc 2048
#define Ec 256
#define Hc 2
#define HDc 128
#define Mrows (Bc*Tc)          // 16384
#define M2c 134

using bfx8  = __attribute__((ext_vector_type(8))) __bf16;
using bfx4  = __attribute__((ext_vector_type(4))) __bf16;
using f32x4 = __attribute__((ext_vector_type(4))) float;

__device__ __forceinline__ void gll16(const __bf16* g, __bf16* lds) {
    __builtin_amdgcn_global_load_lds(
        (const __attribute__((address_space(1))) unsigned int*)g,
        (__attribute__((address_space(3))) unsigned int*)lds, 16, 0, 0);
}

// ---------------- embed + relu + LN1 v2: wave-per-row, no barriers, float4 loads ----------
__global__ __launch_bounds__(256) void embed_prep_k(const float* X, const float* wpe,
                                                    const float* g, const float* bb,
                                                    const float* attn_w, const float* apw,
                                                    const float* fcw, const float* mpw,
                                                    __bf16* wb, float* embsum,
                                                    __bf16* xres, __bf16* hb) {
    int tid = threadIdx.x, w = tid >> 6, l = tid & 63;
    int bidx = blockIdx.x;
    if (bidx < 2048) {
        int i = bidx * 256 + tid;
        if (i < 196608)       wb[i] = (__bf16)attn_w[i];
        else if (i < 262144)  wb[i] = (__bf16)apw[i - 196608];
        else if (i < 393216)  wb[i] = (__bf16)fcw[i - 262144];
        else                  wb[i] = (__bf16)mpw[i - 393216];
        if (bidx < 8) embsum[bidx * 256 + tid] = 0.f;
    }
    int m = bidx * 4 + w;
    int t = m & (Tc - 1);
    int e0 = l * 4;
    float4 x  = *(const float4*)(X   + (size_t)m * Ec + e0);
    float4 p1 = *(const float4*)(wpe + (size_t)t * Ec + e0);
    float4 p2 = *(const float4*)(wpe + (size_t)(t >= 1024 ? Ec : 0) + e0);
    float v0 = fmaxf(x.x + p1.x + p2.x, 0.f);
    float v1 = fmaxf(x.y + p1.y + p2.y, 0.f);
    float v2 = fmaxf(x.z + p1.z + p2.z, 0.f);
    float v3 = fmaxf(x.w + p1.w + p2.w, 0.f);
    bfx4 xq; xq[0] = (__bf16)v0; xq[1] = (__bf16)v1; xq[2] = (__bf16)v2; xq[3] = (__bf16)v3;
    *(bfx4*)(xres + (size_t)m * Ec + e0) = xq;
    float s1 = v0 + v1 + v2 + v3;
    float s2 = v0 * v0 + v1 * v1 + v2 * v2 + v3 * v3;
    #pragma unroll
    for (int o = 32; o; o >>= 1) { s1 += __shfl_xor(s1, o, 64); s2 += __shfl_xor(s2, o, 64); }
    float m1 = s1 * (1.f / 256.f), m2 = s2 * (1.f / 256.f);
    float r = rsqrtf(m2 - m1 * m1 + 1e-5f);
    float4 gg = *(const float4*)(g + e0);
    float4 bv = *(const float4*)(bb + e0);
    bfx4 hq;
    hq[0] = (__bf16)((v0 - m1) * r * gg.x + bv.x);
    hq[1] = (__bf16)((v1 - m1) * r * gg.y + bv.y);
    hq[2] = (__bf16)((v2 - m1) * r * gg.z + bv.z);
    hq[3] = (__bf16)((v3 - m1) * r * gg.w + bv.w);
    *(bfx4*)(hb + (size_t)m * Ec + e0) = hq;
}

// ---------------- B^T GEMM (128x128 tile): qkv epilogue, V transposed in-block ----------
__global__ __launch_bounds__(256) void gemm_qkv(const __bf16* __restrict__ A,
                                                const __bf16* __restrict__ Bw,
                                                const float* __restrict__ bias,
                                                __bf16* __restrict__ Qb,
                                                __bf16* __restrict__ Kb,
                                                __bf16* __restrict__ Vt) {
    const int K = 256;
    __shared__ __attribute__((aligned(16))) __bf16 smem[128 * 136];   // 34.8KB
    __bf16* As = smem;
    __bf16* Bs = smem + 128 * 64;
    const int tid = threadIdx.x, w = tid >> 6, l = tid & 63;
    const int m0 = blockIdx.y * 128, n0 = blockIdx.x * 128;
    const int wr = w >> 1, wc = w & 1;
    const int quad = l >> 4, col15 = l & 15;

    f32x4 acc[4][4];
    f32x4 zz = {0.f, 0.f, 0.f, 0.f};
    #pragma unroll
    for (int i = 0; i < 4; i++)
        #pragma unroll
        for (int j = 0; j < 4; j++) acc[i][j] = zz;

    const int lrow = l >> 3;
    const int pbs  = l & 7;

    for (int kb = 0; kb < K; kb += 64) {
        #pragma unroll
        for (int it = 0; it < 4; it++) {
            int chunk = w * 4 + it;
            int row = chunk * 8 + lrow;
            int lb = pbs ^ (row & 7);
            gll16(A  + (size_t)(m0 + row) * K + kb + lb * 8, As + chunk * 512);
            gll16(Bw + (size_t)(n0 + row) * K + kb + lb * 8, Bs + chunk * 512);
        }
        __syncthreads();
        #pragma unroll
        for (int ks = 0; ks < 2; ks++) {
            bfx8 af[4], bfr[4];
            #pragma unroll
            for (int rt = 0; rt < 4; rt++) {
                int row = wr * 64 + rt * 16 + col15;
                int pb = (ks * 4 + quad) ^ (row & 7);
                af[rt] = *(const bfx8*)(As + row * 64 + pb * 8);
            }
            #pragma unroll
            for (int ct = 0; ct < 4; ct++) {
                int row = wc * 64 + ct * 16 + col15;
                int pb = (ks * 4 + quad) ^ (row & 7);
                bfr[ct] = *(const bfx8*)(Bs + row * 64 + pb * 8);
            }
            #pragma unroll
            for (int rt = 0; rt < 4; rt++)
                #pragma unroll
                for (int ct = 0; ct < 4; ct++)
                    acc[rt][ct] = __builtin_amdgcn_mfma_f32_16x16x32_bf16(af[rt], bfr[ct], acc[rt][ct], 0, 0, 0);
        }
        __syncthreads();
    }

    if (n0 < 512) {
        #pragma unroll
        for (int rt = 0; rt < 4; rt++)
            #pragma unroll
            for (int ct = 0; ct < 4; ct++) {
                int mgb = m0 + wr * 64 + rt * 16 + quad * 4;
                int ng  = n0 + wc * 64 + ct * 16 + col15;
                float bsv = bias[ng];
                #pragma unroll
                for (int r = 0; r < 4; r++) {
                    float val = fmaxf(acc[rt][ct][r] + bsv, 0.f);
                    int mg = mgb + r;
                    int sel = ng >> 8;
                    int hh = (ng >> 7) & 1;
                    int d = ng & 127;
                    int bb2 = mg >> 11, tt = mg & (Tc - 1);
                    size_t idx = ((size_t)((bb2 * 2 + hh) * Tc + tt)) * HDc + d;
                    __bf16 bv = (__bf16)val;
                    if (sel == 0) Qb[idx] = bv;
                    else Kb[idx] = bv;
                }
            }
    } else {
        // V: transpose 128x128 tile through LDS, coalesced store to Vt[bh][d][t]
        int hh = (n0 >> 7) & 1;
        int bh = (m0 >> 11) * 2 + hh;
        int tbase = m0 & (Tc - 1);          // within-batch row base
        #pragma unroll
        for (int rt = 0; rt < 4; rt++)
            #pragma unroll
            for (int ct = 0; ct < 4; ct++) {
                int d  = wc * 64 + ct * 16 + col15;
                float bsv = bias[n0 + wc * 64 + ct * 16 + col15];
                #pragma unroll
                for (int r = 0; r < 4; r++) {
                    int tt = wr * 64 + rt * 16 + quad * 4 + r;
                    float val = fmaxf(acc[rt][ct][r] + bsv, 0.f);
                    smem[d * 136 + tt] = (__bf16)val;
                }
            }
        __syncthreads();
        #pragma unroll
        for (int it = 0; it < 8; it++) {
            int d  = w * 32 + it * 4 + (l >> 4);
            int t0 = (l & 15) * 8;
            bfx8 vv = *(const bfx8*)(smem + d * 136 + t0);
            *(bfx8*)(Vt + ((size_t)(bh * HDc + d)) * Tc + tbase + t0) = vv;
        }
    }
}

// ---------------- causal relu attention v10: swapped-QK S^T fragment -> b64 S-writes ----
// QK computed as mfma(K,Q): lane's C-fragment holds 4 CONSECUTIVE k for one q-row, so the
// S-store packs into 4 ds_write_b64 instead of 16 ds_write_b16 (same swizzled layout the
// PV reads expect). LDS ops per wave-kt: 36 -> 24.
__global__ __launch_bounds__(512, 4) void attn6_k(const __bf16* __restrict__ Qb,
                                                  const __bf16* __restrict__ Kb,
                                                  const __bf16* __restrict__ Vt,
                                                  __bf16* __restrict__ Y1,
                                                  __bf16* __restrict__ Y2,
                                                  __bf16* __restrict__ Y3,
                                                  __bf16* __restrict__ Y4) {
    __shared__ __bf16 Ks[2][64 * 128];   // 32KB (also Q staging area, 128x128 flat)
    __shared__ __bf16 Vs[2][64 * 128];   // 32KB (each buf: 128 d-rows x 64 k-cols)
    __shared__ __bf16 Ss[128 * 64];      // 16KB
    int bid = blockIdx.x;             // 0..639
    int lane8 = bid & 7;
    int s = bid >> 3;                 // 0..79
    int bh = ((s & 1) << 3) | lane8;
    int f = s >> 1;                   // 0..39, heavy q-tiles first
    int qt, ch;
    if (f < 16)      { qt = 12 + (f >> 2);          ch = f & 3; }
    else if (f < 28) { int r = f - 16; int d3 = r / 3; qt = 8 + d3; ch = r - 3 * d3; }
    else if (f < 36) { qt = 4 + ((f - 28) >> 1);    ch = (f - 28) & 1; }
    else             { qt = f - 36;                 ch = 0; }
    int Q0 = qt * 128;
    int kts = ch * 8;
    int kte = min(kts + 8, 2 * qt + 2);

    int tid = threadIdx.x, w = tid >> 6, l = tid & 63;
    int quad = l >> 4, col15 = l & 15;
    const int qs = w >> 1, kh = w & 1;
    const int lrowK = l >> 4, pbsK = l & 15;
    const int lrowV = l >> 3, pbsV = l & 7;

    // stage Q (128x128) into Ks flat
    __bf16* Qs = &Ks[0][0];
    #pragma unroll
    for (int it = 0; it < 4; it++) {
        int chunk = w * 4 + it;           // 0..31
        int row = chunk * 4 + lrowK;      // 0..127
        int lb = pbsK ^ (row & 7);
        gll16(Qb + ((size_t)(bh * Tc + Q0 + row)) * HDc + lb * 8, Qs + chunk * 512);
    }
    __syncthreads();
    bfx8 qf[2][4];
    #pragma unroll
    for (int rt = 0; rt < 2; rt++)
        #pragma unroll
        for (int ks = 0; ks < 4; ks++) {
            int row = qs * 32 + rt * 16 + col15;
            int pb = (ks * 4 + quad) ^ (row & 7);
            qf[rt][ks] = *(const bfx8*)(Qs + row * 128 + pb * 8);
        }
    __syncthreads();   // all waves done reading Q before Ks is restaged

    f32x4 zz = {0.f, 0.f, 0.f, 0.f};
    f32x4 yacc[2][4];
    #pragma unroll
    for (int rt = 0; rt < 2; rt++)
        #pragma unroll
        for (int dt = 0; dt < 4; dt++) yacc[rt][dt] = zz;

    auto stageKV = [&](int buf, int kt) {
        #pragma unroll
        for (int it = 0; it < 2; it++) {
            int chunk = w * 2 + it;       // 0..15
            int rowK = chunk * 4 + lrowK; // 0..63
            int lbK = pbsK ^ (rowK & 7);
            gll16(Kb + ((size_t)(bh * Tc + kt * 64 + rowK)) * HDc + lbK * 8, Ks[buf] + chunk * 512);
            int rowV = chunk * 8 + lrowV; // 0..127
            int lbV = pbsV ^ (rowV & 7);
            gll16(Vt + ((size_t)(bh * HDc + rowV)) * Tc + kt * 64 + lbV * 8, Vs[buf] + chunk * 512);
        }
    };

    stageKV(0, kts);
    int cur = 0;
    for (int kt = kts; kt < kte; kt++) {
        __syncthreads();                       // buf[cur] ready; prior S reads done
        if (kt + 1 < kte) stageKV(cur ^ 1, kt + 1);

        // QK swapped: sacc[ct][rt] = S^T fragment (lane: fixed q=col15-row, k=quad*4+r)
        f32x4 sacc[2][2];
        #pragma unroll
        for (int ct = 0; ct < 2; ct++)
            #pragma unroll
            for (int rt = 0; rt < 2; rt++) sacc[ct][rt] = zz;
        #pragma unroll
        for (int ks = 0; ks < 4; ks++) {
            #pragma unroll
            for (int ct = 0; ct < 2; ct++) {
                int row = kh * 32 + ct * 16 + col15;
                int pb = (ks * 4 + quad) ^ (row & 7);
                bfx8 kf = *(const bfx8*)(Ks[cur] + row * 128 + pb * 8);
                #pragma unroll
                for (int rt = 0; rt < 2; rt++)
                    sacc[ct][rt] = __builtin_amdgcn_mfma_f32_16x16x32_bf16(kf, qf[rt][ks], sacc[ct][rt], 0, 0, 0);
            }
        }

        // mask + relu + packed b64 S-write (4 consecutive k per lane)
        #pragma unroll
        for (int ct = 0; ct < 2; ct++) {
            int kbase = kh * 32 + ct * 16 + quad * 4;      // klocal for r=0
            int kgb = kt * 64 + kbase;
            #pragma unroll
            for (int rt = 0; rt < 2; rt++) {
                int qlocal = qs * 32 + rt * 16 + col15;
                int qg = Q0 + qlocal;
                bfx4 pack;
                #pragma unroll
                for (int r = 0; r < 4; r++) {
                    float val = (kgb + r <= qg) ? fmaxf(sacc[ct][rt][r], 0.f) : 0.f;
                    pack[r] = (__bf16)val;
                }
                int pb = (kbase >> 3) ^ (qlocal & 7);
                *(bfx4*)(Ss + qlocal * 64 + pb * 8 + (kbase & 7)) = pack;
            }
        }

        // S-ready: own writes drained, then raw barrier (no vmcnt drain -> KV prefetch alive)
        asm volatile("s_waitcnt lgkmcnt(0)" ::: "memory");
        __builtin_amdgcn_s_barrier();
        __builtin_amdgcn_sched_barrier(0);

        // PV: yacc[qs rows][kh 64-d half] over full 64 k
        #pragma unroll
        for (int ks = 0; ks < 2; ks++) {
            bfx8 sf[2];
            #pragma unroll
            for (int rt = 0; rt < 2; rt++) {
                int rowS = qs * 32 + rt * 16 + col15;
                int pbS = (ks * 4 + quad) ^ (rowS & 7);
                sf[rt] = *(const bfx8*)(Ss + rowS * 64 + pbS * 8);
            }
            #pragma unroll
            for (int dt = 0; dt < 4; dt++) {
                int rowV = kh * 64 + dt * 16 + col15;
                int pb = (ks * 4 + quad) ^ (rowV & 7);
                bfx8 vf = *(const bfx8*)(Vs[cur] + rowV * 64 + pb * 8);
                #pragma unroll
                for (int rt = 0; rt < 2; rt++)
                    yacc[rt][dt] = __builtin_amdgcn_mfma_f32_16x16x32_bf16(sf[rt], vf, yacc[rt][dt], 0, 0, 0);
            }
        }
        cur ^= 1;
    }

    __bf16* Yp = (ch == 0) ? Y1 : (ch == 1) ? Y2 : (ch == 2) ? Y3 : Y4;
    int b = bh >> 1, h = bh & 1;
    const float sc = 0.08838834764831845f;  // 1/sqrt(128)
    #pragma unroll
    for (int rt = 0; rt < 2; rt++)
        #pragma unroll
        for (int dt = 0; dt < 4; dt++) {
            int d = kh * 64 + dt * 16 + col15;
            #pragma unroll
            for (int r = 0; r < 4; r++) {
                int q = Q0 + qs * 32 + rt * 16 + quad * 4 + r;
                Yp[((size_t)(b * Tc + q)) * Ec + h * HDc + d] = (__bf16)(yacc[rt][dt][r] * sc);
            }
        }
}

// ---------------- MEGA v4: B weights direct-to-register (no Bs LDS), reg double-buffer --
// Each wave reads only its own 32 B-rows; the de-swizzled ds_read address maps 1:1 to
// W[br*stride + kb + (ks*4+quad)*8] -> load the 4 bfx8 fragments per kb straight from
// global (L2-resident weights) into registers, double-buffered one kb ahead. P2/P3 are
// fully barrier- and waitcnt-free at source level. LDS: h2s 32KB + fc64 64KB + ~4.5KB.
__global__ __launch_bounds__(512, 1) void mega_k(const __bf16* __restrict__ Y1,
                                                 const __bf16* __restrict__ Y2,
                                                 const __bf16* __restrict__ Y3,
                                                 const __bf16* __restrict__ Y4,
                                                 const __bf16* __restrict__ wap,
                                                 const float* __restrict__ apb,
                                                 const __bf16* __restrict__ xres,
                                                 const float* __restrict__ ln2_g,
                                                 const float* __restrict__ ln2_b,
                                                 const __bf16* __restrict__ wfc,
                                                 const float* __restrict__ fcb,
                                                 const __bf16* __restrict__ wmp,
                                                 const float* __restrict__ mpb,
                                                 const float* __restrict__ lnf_g,
                                                 const float* __restrict__ lnf_b,
                                                 float* __restrict__ embsum) {
    __shared__ __bf16 h2s[4 * 4096];    // 32KB: 4 panels of 64 rows x 64 cols
    __shared__ __bf16 fc64[8 * 4096];   // 64KB: 8 panels (also aliases As in P1)
    __shared__ float ps1[64][8], ps2[64][8];   // per-wave LN partials
    __shared__ float mus[64], rss[64];
    const int tid = threadIdx.x, w = tid >> 6, l = tid & 63;
    const int m0 = blockIdx.x * 64;
    const int quad = l >> 4, col15 = l & 15;
    const int n0 = w * 32;              // this wave's 32-col group
    f32x4 zz = {0.f, 0.f, 0.f, 0.f};

    const int nsum = (((m0 & (Tc - 1)) >> 6) + 8) >> 3;   // 1..4 Y-partials
    __bf16* As = fc64;   // P1 A-staging aliases fc64 (dead until P2 epilogue)

    const int arow_s = tid >> 3;        // A-staging: row 0..63
    const int ablk   = tid & 7;         // 8-elem block 0..7

    auto loadY = [&](int kb) -> bfx8 {
        size_t off = (size_t)(m0 + arow_s) * 256 + kb + ablk * 8;
        bfx8 a1 = *(const bfx8*)(Y1 + off);
        float tmp[8];
        #pragma unroll
        for (int jj = 0; jj < 8; jj++) tmp[jj] = (float)a1[jj];
        if (nsum > 1) { bfx8 aj = *(const bfx8*)(Y2 + off);
            #pragma unroll
            for (int jj = 0; jj < 8; jj++) tmp[jj] += (float)aj[jj]; }
        if (nsum > 2) { bfx8 aj = *(const bfx8*)(Y3 + off);
            #pragma unroll
            for (int jj = 0; jj < 8; jj++) tmp[jj] += (float)aj[jj]; }
        if (nsum > 3) { bfx8 aj = *(const bfx8*)(Y4 + off);
            #pragma unroll
            for (int jj = 0; jj < 8; jj++) tmp[jj] += (float)aj[jj]; }
        #pragma unroll
        for (int jj = 0; jj < 8; jj++) a1[jj] = (__bf16)tmp[jj];
        return a1;
    };

    // direct-global wave-private B fragment loader (replaces Bs staging + ds_read)
    auto loadB = [&](const __bf16* W, int stride, int kb, bfx8 (&out)[2][2]) {
        #pragma unroll
        for (int ks = 0; ks < 2; ks++)
            #pragma unroll
            for (int ct = 0; ct < 2; ct++) {
                int br = n0 + ct * 16 + col15;
                out[ks][ct] = *(const bfx8*)(W + (size_t)br * stride + kb + (ks * 4 + quad) * 8);
            }
    };

    f32x4 acc[4][2];
    #pragma unroll
    for (int rt = 0; rt < 4; rt++)
        #pragma unroll
        for (int ct = 0; ct < 2; ct++) acc[rt][ct] = zz;

    bfx8 av = loadY(0);
    bfx8 bw[2][2];
    loadB(wap, 256, 0, bw);

    // ---- P1: attnproj C = (sumY) @ wap^T (As cross-wave -> barriers stay; B direct) ----
    for (int kb = 0; kb < 256; kb += 64) {
        __syncthreads();
        { int pb = ablk ^ (arow_s & 7);
          *(bfx8*)(As + arow_s * 64 + pb * 8) = av; }
        bfx8 avn; bfx8 bwn[2][2];
        if (kb < 192) { avn = loadY(kb + 64); loadB(wap, 256, kb + 64, bwn); }
        __syncthreads();
        #pragma unroll
        for (int ks = 0; ks < 2; ks++) {
            bfx8 af[4];
            #pragma unroll
            for (int rt = 0; rt < 4; rt++) {
                int ar = rt * 16 + col15;
                int apbk = (ks * 4 + quad) ^ (ar & 7);
                af[rt] = *(const bfx8*)(As + ar * 64 + apbk * 8);
            }
            #pragma unroll
            for (int ct = 0; ct < 2; ct++)
                #pragma unroll
                for (int rt = 0; rt < 4; rt++)
                    acc[rt][ct] = __builtin_amdgcn_mfma_f32_16x16x32_bf16(af[rt], bw[ks][ct], acc[rt][ct], 0, 0, 0);
        }
        if (kb < 192) {
            av = avn;
            #pragma unroll
            for (int ks = 0; ks < 2; ks++)
                #pragma unroll
                for (int ct = 0; ct < 2; ct++) bw[ks][ct] = bwn[ks][ct];
        }
    }

    // ---- P1 epilogue: x2 = resid + C + bias (f32 in VGPR); h2 = LN2(x2) -> LDS ----
    float xv[4][2][4];
    #pragma unroll
    for (int ct = 0; ct < 2; ct++) {
        int ng = n0 + ct * 16 + col15;
        float bsv = apb[ng];
        #pragma unroll
        for (int rt = 0; rt < 4; rt++)
            #pragma unroll
            for (int r = 0; r < 4; r++) {
                int mg = m0 + rt * 16 + quad * 4 + r;
                xv[rt][ct][r] = acc[rt][ct][r] + bsv + (float)xres[(size_t)mg * 256 + ng];
            }
    }
    #pragma unroll
    for (int rt = 0; rt < 4; rt++)
        #pragma unroll
        for (int r = 0; r < 4; r++) {
            float a  = xv[rt][0][r] + xv[rt][1][r];
            float b2 = xv[rt][0][r] * xv[rt][0][r] + xv[rt][1][r] * xv[rt][1][r];
            #pragma unroll
            for (int o = 1; o < 16; o <<= 1) { a += __shfl_xor(a, o, 64); b2 += __shfl_xor(b2, o, 64); }
            if (col15 == 0) { int row = rt * 16 + quad * 4 + r; ps1[row][w] = a; ps2[row][w] = b2; }
        }
    __syncthreads();
    {
        int row = tid >> 3, widx = tid & 7;
        float a = ps1[row][widx], b2 = ps2[row][widx];
        #pragma unroll
        for (int o = 1; o < 8; o <<= 1) { a += __shfl_xor(a, o, 64); b2 += __shfl_xor(b2, o, 64); }
        if ((l & 7) == 0) {
            float mu = a * (1.f / 256.f);
            float var = b2 * (1.f / 256.f) - mu * mu;
            mus[row] = mu; rss[row] = rsqrtf(var + 1e-5f);
        }
    }
    __syncthreads();
    #pragma unroll
    for (int ct = 0; ct < 2; ct++) {
        int ng = n0 + ct * 16 + col15;
        float gv = ln2_g[ng], bv = ln2_b[ng];
        int panel = ng >> 6, c = ng & 63;
        #pragma unroll
        for (int rt = 0; rt < 4; rt++)
            #pragma unroll
            for (int r = 0; r < 4; r++) {
                int row = rt * 16 + quad * 4 + r;
                float h = (xv[rt][ct][r] - mus[row]) * rss[row] * gv + bv;
                h2s[panel * 4096 + row * 64 + ((c >> 3) ^ (row & 7)) * 8 + (c & 7)] = (__bf16)h;
            }
    }
    __syncthreads();   // h2s visible to all waves before P2 reads

    // ---- P2: fc = relu(h2 @ wfc^T + fcb), two 256-col halves -> fc64 LDS ----
    #pragma unroll
    for (int half = 0; half < 2; half++) {
        const __bf16* Wh = wfc + (size_t)(half * 256) * 256;
        f32x4 acc2[4][2];
        #pragma unroll
        for (int rt = 0; rt < 4; rt++)
            #pragma unroll
            for (int ct = 0; ct < 2; ct++) acc2[rt][ct] = zz;
        bfx8 breg[2][2][2];
        loadB(Wh, 256, 0, breg[0]);
        #pragma unroll
        for (int kb6 = 0; kb6 < 4; kb6++) {
            int cur = kb6 & 1;
            if (kb6 < 3) loadB(Wh, 256, (kb6 + 1) * 64, breg[cur ^ 1]);
            #pragma unroll
            for (int ks = 0; ks < 2; ks++) {
                bfx8 af[4];
                #pragma unroll
                for (int rt = 0; rt < 4; rt++) {
                    int ar = rt * 16 + col15;
                    int apbk = (ks * 4 + quad) ^ (ar & 7);
                    af[rt] = *(const bfx8*)(h2s + kb6 * 4096 + ar * 64 + apbk * 8);
                }
                #pragma unroll
                for (int ct = 0; ct < 2; ct++)
                    #pragma unroll
                    for (int rt = 0; rt < 4; rt++)
                        acc2[rt][ct] = __builtin_amdgcn_mfma_f32_16x16x32_bf16(af[rt], breg[cur][ks][ct], acc2[rt][ct], 0, 0, 0);
            }
        }
        #pragma unroll
        for (int ct = 0; ct < 2; ct++) {
            int col = half * 256 + n0 + ct * 16 + col15;
            float bsv = fcb[col];
            int panel = col >> 6, c = col & 63;
            #pragma unroll
            for (int rt = 0; rt < 4; rt++)
                #pragma unroll
                for (int r = 0; r < 4; r++) {
                    int row = rt * 16 + quad * 4 + r;
                    float val = fmaxf(acc2[rt][ct][r] + bsv, 0.f);
                    fc64[panel * 4096 + row * 64 + ((c >> 3) ^ (row & 7)) * 8 + (c & 7)] = (__bf16)val;
                }
        }
    }
    __syncthreads();   // fc64 visible to all waves before P3 reads

    // ---- P3: mlpproj C = fc64 @ wmp^T ----
    #pragma unroll
    for (int rt = 0; rt < 4; rt++)
        #pragma unroll
        for (int ct = 0; ct < 2; ct++) acc[rt][ct] = zz;
    {
        bfx8 breg[2][2][2];
        loadB(wmp, 512, 0, breg[0]);
        #pragma unroll
        for (int kb6 = 0; kb6 < 8; kb6++) {
            int cur = kb6 & 1;
            if (kb6 < 7) loadB(wmp, 512, (kb6 + 1) * 64, breg[cur ^ 1]);
            #pragma unroll
            for (int ks = 0; ks < 2; ks++) {
                bfx8 af[4];
                #pragma unroll
                for (int rt = 0; rt < 4; rt++) {
                    int ar = rt * 16 + col15;
                    int apbk = (ks * 4 + quad) ^ (ar & 7);
                    af[rt] = *(const bfx8*)(fc64 + kb6 * 4096 + ar * 64 + apbk * 8);
                }
                #pragma unroll
                for (int ct = 0; ct < 2; ct++)
                    #pragma unroll
                    for (int rt = 0; rt < 4; rt++)
                        acc[rt][ct] = __builtin_amdgcn_mfma_f32_16x16x32_bf16(af[rt], breg[cur][ks][ct], acc[rt][ct], 0, 0, 0);
            }
        }
    }

    // ---- P4: x3 = relu(x2 + C + mpb); LNf; xf = relu(LN); column-reduce ----
    #pragma unroll
    for (int ct = 0; ct < 2; ct++) {
        int ng = n0 + ct * 16 + col15;
        float bsv = mpb[ng];
        #pragma unroll
        for (int rt = 0; rt < 4; rt++)
            #pragma unroll
            for (int r = 0; r < 4; r++)
                xv[rt][ct][r] = fmaxf(acc[rt][ct][r] + bsv + xv[rt][ct][r], 0.f);
    }
    #pragma unroll
    for (int rt = 0; rt < 4; rt++)
        #pragma unroll
        for (int r = 0; r < 4; r++) {
            float a  = xv[rt][0][r] + xv[rt][1][r];
            float b2 = xv[rt][0][r] * xv[rt][0][r] + xv[rt][1][r] * xv[rt][1][r];
            #pragma unroll
            for (int o = 1; o < 16; o <<= 1) { a += __shfl_xor(a, o, 64); b2 += __shfl_xor(b2, o, 64); }
            if (col15 == 0) { int row = rt * 16 + quad * 4 + r; ps1[row][w] = a; ps2[row][w] = b2; }
        }
    __syncthreads();
    {
        int row = tid >> 3, widx = tid & 7;
        float a = ps1[row][widx], b2 = ps2[row][widx];
        #pragma unroll
        for (int o = 1; o < 8; o <<= 1) { a += __shfl_xor(a, o, 64); b2 += __shfl_xor(b2, o, 64); }
        if ((l & 7) == 0) {
            float mu = a * (1.f / 256.f);
            float var = b2 * (1.f / 256.f) - mu * mu;
            mus[row] = mu; rss[row] = rsqrtf(var + 1e-5f);
        }
    }
    __syncthreads();
    #pragma unroll
    for (int ct = 0; ct < 2; ct++) {
        int ng = n0 + ct * 16 + col15;
        float gv = lnf_g[ng], bv = lnf_b[ng];
        float csum = 0.f;
        #pragma unroll
        for (int rt = 0; rt < 4; rt++)
            #pragma unroll
            for (int r = 0; r < 4; r++) {
                int row = rt * 16 + quad * 4 + r;
                float h = (xv[rt][ct][r] - mus[row]) * rss[row] * gv + bv;
                csum += fmaxf(h, 0.f);
            }
        csum += __shfl_xor(csum, 16, 64);
        csum += __shfl_xor(csum, 32, 64);
        if (quad == 0) atomicAdd(&embsum[(m0 >> 11) * 256 + ng], csum);
    }
}

// ---------------- final: emb, logits, losses, outputs — FLOAT32 output ----------------
__global__ __launch_bounds__(256) void final_k(const float* embsum, const float* Yt,
                                               const float* head_w, const float* head_b,
                                               float* out) {
    __shared__ float semb[2048];
    __shared__ float slog[1072];
    int tid = threadIdx.x;
    for (int i = tid; i < 2048; i += 256) semb[i] = embsum[i] * (1.f / 2048.f);
    __syncthreads();
    float part1 = 0.f;
    for (int idx = tid; idx < 1072; idx += 256) {
        int b = idx / M2c, n = idx - b * M2c;
        float acc = head_b[n];
        const float* wn = head_w + (size_t)n * Ec;
        const float* e = semb + b * Ec;
        #pragma unroll 8
        for (int k = 0; k < Ec; k++) acc += e[k] * wn[k];
        acc = fmaxf(acc, 0.f);
        slog[idx] = acc;
        float d = acc - Yt[idx];
        part1 += d * d;
    }
    float part3 = 0.f;
    for (int idx = tid; idx < 1024; idx += 256) {
        int b = idx >> 7, i = idx & 127;
        float d = semb[b * Ec + i] - semb[b * Ec + 128 + i];
        part3 += d * d;
    }
    #pragma unroll
    for (int o = 32; o; o >>= 1) { part1 += __shfl_xor(part1, o, 64); part3 += __shfl_xor(part3, o, 64); }
    __shared__ float r1[4], r3[4];
    int w = tid >> 6;
    if ((tid & 63) == 0) { r1[w] = part1; r3[w] = part3; }
    __syncthreads();
    float l1 = sqrtf((r1[0] + r1[1] + r1[2] + r1[3]) / 1072.f);
    float l3 = sqrtf((r3[0] + r3[1] + r3[2] + r3[3]) / 1024.f);
    for (int idx = tid; idx < 1024; idx += 256) {
        int b = idx >> 7, i = idx & 127;
        out[idx]        = semb[b * Ec + i];
        out[1024 + idx] = semb[b * Ec + 128 + i];
    }
    if (tid == 0) {
        out[2048] = 50.f * l1 + l3;
        out[2049] = l1;
        out[2050] = l3;
    }
    for (int idx = tid; idx < 1072; idx += 256) out[2051 + idx] = slog[idx];
}

extern "C" void kernel_launch(void* const* d_in, const int* in_sizes, int n_in,
                              void* d_out, int out_size, void* d_ws, size_t ws_size,
                              hipStream_t stream) {
    const float* X        = (const float*)d_in[0];
    const float* Yt       = (const float*)d_in[1];
    const float* wpe      = (const float*)d_in[2];
    const float* ln1_g    = (const float*)d_in[3];
    const float* ln1_b    = (const float*)d_in[4];
    const float* attn_w   = (const float*)d_in[5];
    const float* attn_b   = (const float*)d_in[6];
    const float* apw      = (const float*)d_in[7];
    const float* apb      = (const float*)d_in[8];
    const float* ln2_g    = (const float*)d_in[9];
    const float* ln2_b    = (const float*)d_in[10];
    const float* fcw      = (const float*)d_in[11];
    const float* fcb      = (const float*)d_in[12];
    const float* mpw      = (const float*)d_in[13];
    const float* mpb      = (const float*)d_in[14];
    const float* lnf_g    = (const float*)d_in[15];
    const float* lnf_b    = (const float*)d_in[16];
    const float* head_w   = (const float*)d_in[17];
    const float* head_b   = (const float*)d_in[18];

    char* ws = (char*)d_ws;
    const size_t MB = 1048576;
    __bf16* xres   = (__bf16*)(ws + 0 * MB);    // 8 MB
    __bf16* hb     = (__bf16*)(ws + 8 * MB);    // 8 MB; later Y3
    __bf16* Qb     = (__bf16*)(ws + 16 * MB);   // 8 MB
    __bf16* Kb     = (__bf16*)(ws + 24 * MB);   // 8 MB
    __bf16* Vb     = (__bf16*)(ws + 32 * MB);   // 8 MB; scratch -> Y4
    __bf16* Vt     = (__bf16*)(ws + 40 * MB);   // 8 MB
    __bf16* Y1     = (__bf16*)(ws + 48 * MB);   // 8 MB
    __bf16* Y2     = (__bf16*)(ws + 56 * MB);   // 8 MB
    __bf16* wb     = (__bf16*)(ws + 64 * MB);   // 1 MB
    float*  embsum = (float*)(ws + 65 * MB);    // 8 KB

    __bf16* Y3 = hb;     // hb dead after gemm_qkv
    __bf16* Y4 = Vb;     // Vb region free (V goes straight to Vt)

    __bf16* wqkv = wb;
    __bf16* wap  = wb + 196608;
    __bf16* wfc  = wb + 262144;
    __bf16* wmp  = wb + 393216;

    embed_prep_k<<<4096, 256, 0, stream>>>(X, wpe, ln1_g, ln1_b,
                                           attn_w, apw, fcw, mpw, wb, embsum, xres, hb);
    gemm_qkv<<<dim3(6, 128), 256, 0, stream>>>(hb, wqkv, attn_b, Qb, Kb, Vt);
    attn6_k<<<640, 512, 0, stream>>>(Qb, Kb, Vt, Y1, Y2, Y3, Y4);
    mega_k<<<256, 512, 0, stream>>>(Y1, Y2, Y3, Y4, wap, apb, xres, ln2_g, ln2_b,
                                    wfc, fcb, wmp, mpb, lnf_g, lnf_b, embsum);
    final_k<<<1, 256, 0, stream>>>(embsum, Yt, head_w, head_b, (float*)d_out);
}

// Round 8
// 215.364 us; speedup vs baseline: 1.0415x; 1.0415x over previous
//
#include <hip/hip_runtime.h>
#include <hip/hip_bf16.h>

// Problem constants
#define Bc 8
#define Tc 2048
#define Ec 256
#define Hc 2
#define HDc 128
#define Mrows (Bc*Tc)          // 16384
#define M2c 134

using bfx8  = __attribute__((ext_vector_type(8))) __bf16;
using bfx4  = __attribute__((ext_vector_type(4))) __bf16;
using f32x4 = __attribute__((ext_vector_type(4))) float;

__device__ __forceinline__ void gll16(const __bf16* g, __bf16* lds) {
    __builtin_amdgcn_global_load_lds(
        (const __attribute__((address_space(1))) unsigned int*)g,
        (__attribute__((address_space(3))) unsigned int*)lds, 16, 0, 0);
}

// ---------------- embed + relu + LN1 v2: wave-per-row, no barriers, float4 loads ----------
__global__ __launch_bounds__(256) void embed_prep_k(const float* X, const float* wpe,
                                                    const float* g, const float* bb,
                                                    const float* attn_w, const float* apw,
                                                    const float* fcw, const float* mpw,
                                                    __bf16* wb, float* embsum,
                                                    __bf16* xres, __bf16* hb) {
    int tid = threadIdx.x, w = tid >> 6, l = tid & 63;
    int bidx = blockIdx.x;
    if (bidx < 2048) {
        int i = bidx * 256 + tid;
        if (i < 196608)       wb[i] = (__bf16)attn_w[i];
        else if (i < 262144)  wb[i] = (__bf16)apw[i - 196608];
        else if (i < 393216)  wb[i] = (__bf16)fcw[i - 262144];
        else                  wb[i] = (__bf16)mpw[i - 393216];
        if (bidx < 8) embsum[bidx * 256 + tid] = 0.f;
    }
    int m = bidx * 4 + w;
    int t = m & (Tc - 1);
    int e0 = l * 4;
    float4 x  = *(const float4*)(X   + (size_t)m * Ec + e0);
    float4 p1 = *(const float4*)(wpe + (size_t)t * Ec + e0);
    float4 p2 = *(const float4*)(wpe + (size_t)(t >= 1024 ? Ec : 0) + e0);
    float v0 = fmaxf(x.x + p1.x + p2.x, 0.f);
    float v1 = fmaxf(x.y + p1.y + p2.y, 0.f);
    float v2 = fmaxf(x.z + p1.z + p2.z, 0.f);
    float v3 = fmaxf(x.w + p1.w + p2.w, 0.f);
    bfx4 xq; xq[0] = (__bf16)v0; xq[1] = (__bf16)v1; xq[2] = (__bf16)v2; xq[3] = (__bf16)v3;
    *(bfx4*)(xres + (size_t)m * Ec + e0) = xq;
    float s1 = v0 + v1 + v2 + v3;
    float s2 = v0 * v0 + v1 * v1 + v2 * v2 + v3 * v3;
    #pragma unroll
    for (int o = 32; o; o >>= 1) { s1 += __shfl_xor(s1, o, 64); s2 += __shfl_xor(s2, o, 64); }
    float m1 = s1 * (1.f / 256.f), m2 = s2 * (1.f / 256.f);
    float r = rsqrtf(m2 - m1 * m1 + 1e-5f);
    float4 gg = *(const float4*)(g + e0);
    float4 bv = *(const float4*)(bb + e0);
    bfx4 hq;
    hq[0] = (__bf16)((v0 - m1) * r * gg.x + bv.x);
    hq[1] = (__bf16)((v1 - m1) * r * gg.y + bv.y);
    hq[2] = (__bf16)((v2 - m1) * r * gg.z + bv.z);
    hq[3] = (__bf16)((v3 - m1) * r * gg.w + bv.w);
    *(bfx4*)(hb + (size_t)m * Ec + e0) = hq;
}

// ---------------- B^T GEMM (128x128 tile): qkv epilogue, V transposed in-block ----------
__global__ __launch_bounds__(256) void gemm_qkv(const __bf16* __restrict__ A,
                                                const __bf16* __restrict__ Bw,
                                                const float* __restrict__ bias,
                                                __bf16* __restrict__ Qb,
                                                __bf16* __restrict__ Kb,
                                                __bf16* __restrict__ Vt) {
    const int K = 256;
    __shared__ __attribute__((aligned(16))) __bf16 smem[128 * 136];   // 34.8KB
    __bf16* As = smem;
    __bf16* Bs = smem + 128 * 64;
    const int tid = threadIdx.x, w = tid >> 6, l = tid & 63;
    const int m0 = blockIdx.y * 128, n0 = blockIdx.x * 128;
    const int wr = w >> 1, wc = w & 1;
    const int quad = l >> 4, col15 = l & 15;

    f32x4 acc[4][4];
    f32x4 zz = {0.f, 0.f, 0.f, 0.f};
    #pragma unroll
    for (int i = 0; i < 4; i++)
        #pragma unroll
        for (int j = 0; j < 4; j++) acc[i][j] = zz;

    const int lrow = l >> 3;
    const int pbs  = l & 7;

    for (int kb = 0; kb < K; kb += 64) {
        #pragma unroll
        for (int it = 0; it < 4; it++) {
            int chunk = w * 4 + it;
            int row = chunk * 8 + lrow;
            int lb = pbs ^ (row & 7);
            gll16(A  + (size_t)(m0 + row) * K + kb + lb * 8, As + chunk * 512);
            gll16(Bw + (size_t)(n0 + row) * K + kb + lb * 8, Bs + chunk * 512);
        }
        __syncthreads();
        #pragma unroll
        for (int ks = 0; ks < 2; ks++) {
            bfx8 af[4], bfr[4];
            #pragma unroll
            for (int rt = 0; rt < 4; rt++) {
                int row = wr * 64 + rt * 16 + col15;
                int pb = (ks * 4 + quad) ^ (row & 7);
                af[rt] = *(const bfx8*)(As + row * 64 + pb * 8);
            }
            #pragma unroll
            for (int ct = 0; ct < 4; ct++) {
                int row = wc * 64 + ct * 16 + col15;
                int pb = (ks * 4 + quad) ^ (row & 7);
                bfr[ct] = *(const bfx8*)(Bs + row * 64 + pb * 8);
            }
            #pragma unroll
            for (int rt = 0; rt < 4; rt++)
                #pragma unroll
                for (int ct = 0; ct < 4; ct++)
                    acc[rt][ct] = __builtin_amdgcn_mfma_f32_16x16x32_bf16(af[rt], bfr[ct], acc[rt][ct], 0, 0, 0);
        }
        __syncthreads();
    }

    if (n0 < 512) {
        #pragma unroll
        for (int rt = 0; rt < 4; rt++)
            #pragma unroll
            for (int ct = 0; ct < 4; ct++) {
                int mgb = m0 + wr * 64 + rt * 16 + quad * 4;
                int ng  = n0 + wc * 64 + ct * 16 + col15;
                float bsv = bias[ng];
                #pragma unroll
                for (int r = 0; r < 4; r++) {
                    float val = fmaxf(acc[rt][ct][r] + bsv, 0.f);
                    int mg = mgb + r;
                    int sel = ng >> 8;
                    int hh = (ng >> 7) & 1;
                    int d = ng & 127;
                    int bb2 = mg >> 11, tt = mg & (Tc - 1);
                    size_t idx = ((size_t)((bb2 * 2 + hh) * Tc + tt)) * HDc + d;
                    __bf16 bv = (__bf16)val;
                    if (sel == 0) Qb[idx] = bv;
                    else Kb[idx] = bv;
                }
            }
    } else {
        // V: transpose 128x128 tile through LDS, coalesced store to Vt[bh][d][t]
        int hh = (n0 >> 7) & 1;
        int bh = (m0 >> 11) * 2 + hh;
        int tbase = m0 & (Tc - 1);          // within-batch row base
        #pragma unroll
        for (int rt = 0; rt < 4; rt++)
            #pragma unroll
            for (int ct = 0; ct < 4; ct++) {
                int d  = wc * 64 + ct * 16 + col15;
                float bsv = bias[n0 + wc * 64 + ct * 16 + col15];
                #pragma unroll
                for (int r = 0; r < 4; r++) {
                    int tt = wr * 64 + rt * 16 + quad * 4 + r;
                    float val = fmaxf(acc[rt][ct][r] + bsv, 0.f);
                    smem[d * 136 + tt] = (__bf16)val;
                }
            }
        __syncthreads();
        #pragma unroll
        for (int it = 0; it < 8; it++) {
            int d  = w * 32 + it * 4 + (l >> 4);
            int t0 = (l & 15) * 8;
            bfx8 vv = *(const bfx8*)(smem + d * 136 + t0);
            *(bfx8*)(Vt + ((size_t)(bh * HDc + d)) * Tc + tbase + t0) = vv;
        }
    }
}

// ---------------- causal relu attention v10: swapped-QK S^T fragment -> b64 S-writes ----
// (kept from R6 — functionally verified; isolating it vs R5's v9 this round)
__global__ __launch_bounds__(512, 4) void attn6_k(const __bf16* __restrict__ Qb,
                                                  const __bf16* __restrict__ Kb,
                                                  const __bf16* __restrict__ Vt,
                                                  __bf16* __restrict__ Y1,
                                                  __bf16* __restrict__ Y2,
                                                  __bf16* __restrict__ Y3,
                                                  __bf16* __restrict__ Y4) {
    __shared__ __bf16 Ks[2][64 * 128];   // 32KB (also Q staging area, 128x128 flat)
    __shared__ __bf16 Vs[2][64 * 128];   // 32KB (each buf: 128 d-rows x 64 k-cols)
    __shared__ __bf16 Ss[128 * 64];      // 16KB
    int bid = blockIdx.x;             // 0..639
    int lane8 = bid & 7;
    int s = bid >> 3;                 // 0..79
    int bh = ((s & 1) << 3) | lane8;
    int f = s >> 1;                   // 0..39, heavy q-tiles first
    int qt, ch;
    if (f < 16)      { qt = 12 + (f >> 2);          ch = f & 3; }
    else if (f < 28) { int r = f - 16; int d3 = r / 3; qt = 8 + d3; ch = r - 3 * d3; }
    else if (f < 36) { qt = 4 + ((f - 28) >> 1);    ch = (f - 28) & 1; }
    else             { qt = f - 36;                 ch = 0; }
    int Q0 = qt * 128;
    int kts = ch * 8;
    int kte = min(kts + 8, 2 * qt + 2);

    int tid = threadIdx.x, w = tid >> 6, l = tid & 63;
    int quad = l >> 4, col15 = l & 15;
    const int qs = w >> 1, kh = w & 1;
    const int lrowK = l >> 4, pbsK = l & 15;
    const int lrowV = l >> 3, pbsV = l & 7;

    // stage Q (128x128) into Ks flat
    __bf16* Qs = &Ks[0][0];
    #pragma unroll
    for (int it = 0; it < 4; it++) {
        int chunk = w * 4 + it;           // 0..31
        int row = chunk * 4 + lrowK;      // 0..127
        int lb = pbsK ^ (row & 7);
        gll16(Qb + ((size_t)(bh * Tc + Q0 + row)) * HDc + lb * 8, Qs + chunk * 512);
    }
    __syncthreads();
    bfx8 qf[2][4];
    #pragma unroll
    for (int rt = 0; rt < 2; rt++)
        #pragma unroll
        for (int ks = 0; ks < 4; ks++) {
            int row = qs * 32 + rt * 16 + col15;
            int pb = (ks * 4 + quad) ^ (row & 7);
            qf[rt][ks] = *(const bfx8*)(Qs + row * 128 + pb * 8);
        }
    __syncthreads();   // all waves done reading Q before Ks is restaged

    f32x4 zz = {0.f, 0.f, 0.f, 0.f};
    f32x4 yacc[2][4];
    #pragma unroll
    for (int rt = 0; rt < 2; rt++)
        #pragma unroll
        for (int dt = 0; dt < 4; dt++) yacc[rt][dt] = zz;

    auto stageKV = [&](int buf, int kt) {
        #pragma unroll
        for (int it = 0; it < 2; it++) {
            int chunk = w * 2 + it;       // 0..15
            int rowK = chunk * 4 + lrowK; // 0..63
            int lbK = pbsK ^ (rowK & 7);
            gll16(Kb + ((size_t)(bh * Tc + kt * 64 + rowK)) * HDc + lbK * 8, Ks[buf] + chunk * 512);
            int rowV = chunk * 8 + lrowV; // 0..127
            int lbV = pbsV ^ (rowV & 7);
            gll16(Vt + ((size_t)(bh * HDc + rowV)) * Tc + kt * 64 + lbV * 8, Vs[buf] + chunk * 512);
        }
    };

    stageKV(0, kts);
    int cur = 0;
    for (int kt = kts; kt < kte; kt++) {
        __syncthreads();                       // buf[cur] ready; prior S reads done
        if (kt + 1 < kte) stageKV(cur ^ 1, kt + 1);

        // QK swapped: sacc[ct][rt] = S^T fragment (lane: fixed q=col15-row, k=quad*4+r)
        f32x4 sacc[2][2];
        #pragma unroll
        for (int ct = 0; ct < 2; ct++)
            #pragma unroll
            for (int rt = 0; rt < 2; rt++) sacc[ct][rt] = zz;
        #pragma unroll
        for (int ks = 0; ks < 4; ks++) {
            #pragma unroll
            for (int ct = 0; ct < 2; ct++) {
                int row = kh * 32 + ct * 16 + col15;
                int pb = (ks * 4 + quad) ^ (row & 7);
                bfx8 kf = *(const bfx8*)(Ks[cur] + row * 128 + pb * 8);
                #pragma unroll
                for (int rt = 0; rt < 2; rt++)
                    sacc[ct][rt] = __builtin_amdgcn_mfma_f32_16x16x32_bf16(kf, qf[rt][ks], sacc[ct][rt], 0, 0, 0);
            }
        }

        // mask + relu + packed b64 S-write (4 consecutive k per lane)
        #pragma unroll
        for (int ct = 0; ct < 2; ct++) {
            int kbase = kh * 32 + ct * 16 + quad * 4;      // klocal for r=0
            int kgb = kt * 64 + kbase;
            #pragma unroll
            for (int rt = 0; rt < 2; rt++) {
                int qlocal = qs * 32 + rt * 16 + col15;
                int qg = Q0 + qlocal;
                bfx4 pack;
                #pragma unroll
                for (int r = 0; r < 4; r++) {
                    float val = (kgb + r <= qg) ? fmaxf(sacc[ct][rt][r], 0.f) : 0.f;
                    pack[r] = (__bf16)val;
                }
                int pb = (kbase >> 3) ^ (qlocal & 7);
                *(bfx4*)(Ss + qlocal * 64 + pb * 8 + (kbase & 7)) = pack;
            }
        }

        // S-ready: own writes drained, then raw barrier (no vmcnt drain -> KV prefetch alive)
        asm volatile("s_waitcnt lgkmcnt(0)" ::: "memory");
        __builtin_amdgcn_s_barrier();
        __builtin_amdgcn_sched_barrier(0);

        // PV: yacc[qs rows][kh 64-d half] over full 64 k
        #pragma unroll
        for (int ks = 0; ks < 2; ks++) {
            bfx8 sf[2];
            #pragma unroll
            for (int rt = 0; rt < 2; rt++) {
                int rowS = qs * 32 + rt * 16 + col15;
                int pbS = (ks * 4 + quad) ^ (rowS & 7);
                sf[rt] = *(const bfx8*)(Ss + rowS * 64 + pbS * 8);
            }
            #pragma unroll
            for (int dt = 0; dt < 4; dt++) {
                int rowV = kh * 64 + dt * 16 + col15;
                int pb = (ks * 4 + quad) ^ (rowV & 7);
                bfx8 vf = *(const bfx8*)(Vs[cur] + rowV * 64 + pb * 8);
                #pragma unroll
                for (int rt = 0; rt < 2; rt++)
                    yacc[rt][dt] = __builtin_amdgcn_mfma_f32_16x16x32_bf16(sf[rt], vf, yacc[rt][dt], 0, 0, 0);
            }
        }
        cur ^= 1;
    }

    __bf16* Yp = (ch == 0) ? Y1 : (ch == 1) ? Y2 : (ch == 2) ? Y3 : Y4;
    int b = bh >> 1, h = bh & 1;
    const float sc = 0.08838834764831845f;  // 1/sqrt(128)
    #pragma unroll
    for (int rt = 0; rt < 2; rt++)
        #pragma unroll
        for (int dt = 0; dt < 4; dt++) {
            int d = kh * 64 + dt * 16 + col15;
            #pragma unroll
            for (int r = 0; r < 4; r++) {
                int q = Q0 + qs * 32 + rt * 16 + quad * 4 + r;
                Yp[((size_t)(b * Tc + q)) * Ec + h * HDc + d] = (__bf16)(yacc[rt][dt][r] * sc);
            }
        }
}

// ---------------- MEGA v3 (restored from R5): wave-private Bs, barrier-free P2/P3 ------
__global__ __launch_bounds__(512, 1) void mega_k(const __bf16* __restrict__ Y1,
                                                 const __bf16* __restrict__ Y2,
                                                 const __bf16* __restrict__ Y3,
                                                 const __bf16* __restrict__ Y4,
                                                 const __bf16* __restrict__ wap,
                                                 const float* __restrict__ apb,
                                                 const __bf16* __restrict__ xres,
                                                 const float* __restrict__ ln2_g,
                                                 const float* __restrict__ ln2_b,
                                                 const __bf16* __restrict__ wfc,
                                                 const float* __restrict__ fcb,
                                                 const __bf16* __restrict__ wmp,
                                                 const float* __restrict__ mpb,
                                                 const float* __restrict__ lnf_g,
                                                 const float* __restrict__ lnf_b,
                                                 float* __restrict__ embsum) {
    __shared__ __bf16 h2s[4 * 4096];    // 32KB: 4 panels of 64 rows x 64 cols
    __shared__ __bf16 fc64[8 * 4096];   // 64KB: 8 panels (also aliases As in P1)
    __shared__ __bf16 Bs[256 * 64];     // 32KB
    __shared__ float ps1[64][8], ps2[64][8];   // per-wave LN partials
    __shared__ float mus[64], rss[64];
    const int tid = threadIdx.x, w = tid >> 6, l = tid & 63;
    const int m0 = blockIdx.x * 64;
    const int quad = l >> 4, col15 = l & 15;
    const int lrow = l >> 3, pbs = l & 7;
    const int n0 = w * 32;              // this wave's 32-col group
    f32x4 zz = {0.f, 0.f, 0.f, 0.f};

    const int nsum = (((m0 & (Tc - 1)) >> 6) + 8) >> 3;   // 1..4 Y-partials
    __bf16* As = fc64;   // P1 A-staging aliases fc64 (dead until P2 epilogue)

    const int arow_s = tid >> 3;        // A-staging: row 0..63
    const int ablk   = tid & 7;         // 8-elem block 0..7

    auto loadY = [&](int kb) -> bfx8 {
        size_t off = (size_t)(m0 + arow_s) * 256 + kb + ablk * 8;
        bfx8 a1 = *(const bfx8*)(Y1 + off);
        float tmp[8];
        #pragma unroll
        for (int jj = 0; jj < 8; jj++) tmp[jj] = (float)a1[jj];
        if (nsum > 1) { bfx8 aj = *(const bfx8*)(Y2 + off);
            #pragma unroll
            for (int jj = 0; jj < 8; jj++) tmp[jj] += (float)aj[jj]; }
        if (nsum > 2) { bfx8 aj = *(const bfx8*)(Y3 + off);
            #pragma unroll
            for (int jj = 0; jj < 8; jj++) tmp[jj] += (float)aj[jj]; }
        if (nsum > 3) { bfx8 aj = *(const bfx8*)(Y4 + off);
            #pragma unroll
            for (int jj = 0; jj < 8; jj++) tmp[jj] += (float)aj[jj]; }
        #pragma unroll
        for (int jj = 0; jj < 8; jj++) a1[jj] = (__bf16)tmp[jj];
        return a1;
    };

    f32x4 acc[4][2];
    #pragma unroll
    for (int rt = 0; rt < 4; rt++)
        #pragma unroll
        for (int ct = 0; ct < 2; ct++) acc[rt][ct] = zz;

    bfx8 av = loadY(0);

    // ---- P1: attnproj C = (sumY) @ wap^T (As cross-wave -> barriers stay) ----
    for (int kb = 0; kb < 256; kb += 64) {
        __syncthreads();
        { int pb = ablk ^ (arow_s & 7);
          *(bfx8*)(As + arow_s * 64 + pb * 8) = av; }
        #pragma unroll
        for (int it = 0; it < 4; it++) {
            int chunk = w * 4 + it;
            int row = chunk * 8 + lrow;
            int lb = pbs ^ (row & 7);
            gll16(wap + (size_t)row * 256 + kb + lb * 8, Bs + chunk * 512);
        }
        bfx8 avn;
        if (kb < 192) avn = loadY(kb + 64);   // overlaps with gll16 drain
        __syncthreads();
        #pragma unroll
        for (int ks = 0; ks < 2; ks++) {
            bfx8 af[4];
            #pragma unroll
            for (int rt = 0; rt < 4; rt++) {
                int ar = rt * 16 + col15;
                int apbk = (ks * 4 + quad) ^ (ar & 7);
                af[rt] = *(const bfx8*)(As + ar * 64 + apbk * 8);
            }
            #pragma unroll
            for (int ct = 0; ct < 2; ct++) {
                int br = n0 + ct * 16 + col15;
                int bpb = (ks * 4 + quad) ^ (br & 7);
                bfx8 bf = *(const bfx8*)(Bs + br * 64 + bpb * 8);
                #pragma unroll
                for (int rt = 0; rt < 4; rt++)
                    acc[rt][ct] = __builtin_amdgcn_mfma_f32_16x16x32_bf16(af[rt], bf, acc[rt][ct], 0, 0, 0);
            }
        }
        if (kb < 192) av = avn;
    }

    // ---- P1 epilogue: x2 = resid + C + bias (f32 in VGPR); h2 = LN2(x2) -> LDS ----
    float xv[4][2][4];
    #pragma unroll
    for (int ct = 0; ct < 2; ct++) {
        int ng = n0 + ct * 16 + col15;
        float bsv = apb[ng];
        #pragma unroll
        for (int rt = 0; rt < 4; rt++)
            #pragma unroll
            for (int r = 0; r < 4; r++) {
                int mg = m0 + rt * 16 + quad * 4 + r;
                xv[rt][ct][r] = acc[rt][ct][r] + bsv + (float)xres[(size_t)mg * 256 + ng];
            }
    }
    #pragma unroll
    for (int rt = 0; rt < 4; rt++)
        #pragma unroll
        for (int r = 0; r < 4; r++) {
            float a  = xv[rt][0][r] + xv[rt][1][r];
            float b2 = xv[rt][0][r] * xv[rt][0][r] + xv[rt][1][r] * xv[rt][1][r];
            #pragma unroll
            for (int o = 1; o < 16; o <<= 1) { a += __shfl_xor(a, o, 64); b2 += __shfl_xor(b2, o, 64); }
            if (col15 == 0) { int row = rt * 16 + quad * 4 + r; ps1[row][w] = a; ps2[row][w] = b2; }
        }
    __syncthreads();
    {
        int row = tid >> 3, widx = tid & 7;
        float a = ps1[row][widx], b2 = ps2[row][widx];
        #pragma unroll
        for (int o = 1; o < 8; o <<= 1) { a += __shfl_xor(a, o, 64); b2 += __shfl_xor(b2, o, 64); }
        if ((l & 7) == 0) {
            float mu = a * (1.f / 256.f);
            float var = b2 * (1.f / 256.f) - mu * mu;
            mus[row] = mu; rss[row] = rsqrtf(var + 1e-5f);
        }
    }
    __syncthreads();
    #pragma unroll
    for (int ct = 0; ct < 2; ct++) {
        int ng = n0 + ct * 16 + col15;
        float gv = ln2_g[ng], bv = ln2_b[ng];
        int panel = ng >> 6, c = ng & 63;
        #pragma unroll
        for (int rt = 0; rt < 4; rt++)
            #pragma unroll
            for (int r = 0; r < 4; r++) {
                int row = rt * 16 + quad * 4 + r;
                float h = (xv[rt][ct][r] - mus[row]) * rss[row] * gv + bv;
                h2s[panel * 4096 + row * 64 + ((c >> 3) ^ (row & 7)) * 8 + (c & 7)] = (__bf16)h;
            }
    }
    __syncthreads();   // h2s visible to all waves before P2 reads (P2 loop is barrier-free)

    // ---- P2: fc = relu(h2 @ wfc^T + fcb), two 256-col halves -> fc64 LDS ----
    for (int half = 0; half < 2; half++) {
        f32x4 acc2[4][2];
        #pragma unroll
        for (int rt = 0; rt < 4; rt++)
            #pragma unroll
            for (int ct = 0; ct < 2; ct++) acc2[rt][ct] = zz;
        for (int kb = 0; kb < 256; kb += 64) {
            asm volatile("s_waitcnt lgkmcnt(0)" ::: "memory");   // own Bs reads done
            #pragma unroll
            for (int it = 0; it < 4; it++) {
                int chunk = w * 4 + it;
                int row = chunk * 8 + lrow;
                int lb = pbs ^ (row & 7);
                gll16(wfc + (size_t)(half * 256 + row) * 256 + kb + lb * 8, Bs + chunk * 512);
            }
            asm volatile("s_waitcnt vmcnt(0)" ::: "memory");     // own stages landed
            __builtin_amdgcn_sched_barrier(0);
            int panel = kb >> 6;
            #pragma unroll
            for (int ks = 0; ks < 2; ks++) {
                bfx8 af[4];
                #pragma unroll
                for (int rt = 0; rt < 4; rt++) {
                    int ar = rt * 16 + col15;
                    int apbk = (ks * 4 + quad) ^ (ar & 7);
                    af[rt] = *(const bfx8*)(h2s + panel * 4096 + ar * 64 + apbk * 8);
                }
                #pragma unroll
                for (int ct = 0; ct < 2; ct++) {
                    int br = n0 + ct * 16 + col15;
                    int bpb = (ks * 4 + quad) ^ (br & 7);
                    bfx8 bf = *(const bfx8*)(Bs + br * 64 + bpb * 8);
                    #pragma unroll
                    for (int rt = 0; rt < 4; rt++)
                        acc2[rt][ct] = __builtin_amdgcn_mfma_f32_16x16x32_bf16(af[rt], bf, acc2[rt][ct], 0, 0, 0);
                }
            }
        }
        #pragma unroll
        for (int ct = 0; ct < 2; ct++) {
            int col = half * 256 + n0 + ct * 16 + col15;
            float bsv = fcb[col];
            int panel = col >> 6, c = col & 63;
            #pragma unroll
            for (int rt = 0; rt < 4; rt++)
                #pragma unroll
                for (int r = 0; r < 4; r++) {
                    int row = rt * 16 + quad * 4 + r;
                    float val = fmaxf(acc2[rt][ct][r] + bsv, 0.f);
                    fc64[panel * 4096 + row * 64 + ((c >> 3) ^ (row & 7)) * 8 + (c & 7)] = (__bf16)val;
                }
        }
    }
    __syncthreads();   // fc64 visible to all waves before P3 reads (P3 loop is barrier-free)

    // ---- P3: mlpproj C = fc64 @ wmp^T ----
    #pragma unroll
    for (int rt = 0; rt < 4; rt++)
        #pragma unroll
        for (int ct = 0; ct < 2; ct++) acc[rt][ct] = zz;
    for (int kb = 0; kb < 512; kb += 64) {
        asm volatile("s_waitcnt lgkmcnt(0)" ::: "memory");   // own Bs reads done
        #pragma unroll
        for (int it = 0; it < 4; it++) {
            int chunk = w * 4 + it;
            int row = chunk * 8 + lrow;
            int lb = pbs ^ (row & 7);
            gll16(wmp + (size_t)row * 512 + kb + lb * 8, Bs + chunk * 512);
        }
        asm volatile("s_waitcnt vmcnt(0)" ::: "memory");     // own stages landed
        __builtin_amdgcn_sched_barrier(0);
        int panel = kb >> 6;
        #pragma unroll
        for (int ks = 0; ks < 2; ks++) {
            bfx8 af[4];
            #pragma unroll
            for (int rt = 0; rt < 4; rt++) {
                int ar = rt * 16 + col15;
                int apbk = (ks * 4 + quad) ^ (ar & 7);
                af[rt] = *(const bfx8*)(fc64 + panel * 4096 + ar * 64 + apbk * 8);
            }
            #pragma unroll
            for (int ct = 0; ct < 2; ct++) {
                int br = n0 + ct * 16 + col15;
                int bpb = (ks * 4 + quad) ^ (br & 7);
                bfx8 bf = *(const bfx8*)(Bs + br * 64 + bpb * 8);
                #pragma unroll
                for (int rt = 0; rt < 4; rt++)
                    acc[rt][ct] = __builtin_amdgcn_mfma_f32_16x16x32_bf16(af[rt], bf, acc[rt][ct], 0, 0, 0);
            }
        }
    }

    // ---- P4: x3 = relu(x2 + C + mpb); LNf; xf = relu(LN); column-reduce ----
    #pragma unroll
    for (int ct = 0; ct < 2; ct++) {
        int ng = n0 + ct * 16 + col15;
        float bsv = mpb[ng];
        #pragma unroll
        for (int rt = 0; rt < 4; rt++)
            #pragma unroll
            for (int r = 0; r < 4; r++)
                xv[rt][ct][r] = fmaxf(acc[rt][ct][r] + bsv + xv[rt][ct][r], 0.f);
    }
    #pragma unroll
    for (int rt = 0; rt < 4; rt++)
        #pragma unroll
        for (int r = 0; r < 4; r++) {
            float a  = xv[rt][0][r] + xv[rt][1][r];
            float b2 = xv[rt][0][r] * xv[rt][0][r] + xv[rt][1][r] * xv[rt][1][r];
            #pragma unroll
            for (int o = 1; o < 16; o <<= 1) { a += __shfl_xor(a, o, 64); b2 += __shfl_xor(b2, o, 64); }
            if (col15 == 0) { int row = rt * 16 + quad * 4 + r; ps1[row][w] = a; ps2[row][w] = b2; }
        }
    __syncthreads();
    {
        int row = tid >> 3, widx = tid & 7;
        float a = ps1[row][widx], b2 = ps2[row][widx];
        #pragma unroll
        for (int o = 1; o < 8; o <<= 1) { a += __shfl_xor(a, o, 64); b2 += __shfl_xor(b2, o, 64); }
        if ((l & 7) == 0) {
            float mu = a * (1.f / 256.f);
            float var = b2 * (1.f / 256.f) - mu * mu;
            mus[row] = mu; rss[row] = rsqrtf(var + 1e-5f);
        }
    }
    __syncthreads();
    #pragma unroll
    for (int ct = 0; ct < 2; ct++) {
        int ng = n0 + ct * 16 + col15;
        float gv = lnf_g[ng], bv = lnf_b[ng];
        float csum = 0.f;
        #pragma unroll
        for (int rt = 0; rt < 4; rt++)
            #pragma unroll
            for (int r = 0; r < 4; r++) {
                int row = rt * 16 + quad * 4 + r;
                float h = (xv[rt][ct][r] - mus[row]) * rss[row] * gv + bv;
                csum += fmaxf(h, 0.f);
            }
        csum += __shfl_xor(csum, 16, 64);
        csum += __shfl_xor(csum, 32, 64);
        if (quad == 0) atomicAdd(&embsum[(m0 >> 11) * 256 + ng], csum);
    }
}

// ---------------- final: emb, logits, losses, outputs — FLOAT32 output ----------------
__global__ __launch_bounds__(256) void final_k(const float* embsum, const float* Yt,
                                               const float* head_w, const float* head_b,
                                               float* out) {
    __shared__ float semb[2048];
    __shared__ float slog[1072];
    int tid = threadIdx.x;
    for (int i = tid; i < 2048; i += 256) semb[i] = embsum[i] * (1.f / 2048.f);
    __syncthreads();
    float part1 = 0.f;
    for (int idx = tid; idx < 1072; idx += 256) {
        int b = idx / M2c, n = idx - b * M2c;
        float acc = head_b[n];
        const float* wn = head_w + (size_t)n * Ec;
        const float* e = semb + b * Ec;
        #pragma unroll 8
        for (int k = 0; k < Ec; k++) acc += e[k] * wn[k];
        acc = fmaxf(acc, 0.f);
        slog[idx] = acc;
        float d = acc - Yt[idx];
        part1 += d * d;
    }
    float part3 = 0.f;
    for (int idx = tid; idx < 1024; idx += 256) {
        int b = idx >> 7, i = idx & 127;
        float d = semb[b * Ec + i] - semb[b * Ec + 128 + i];
        part3 += d * d;
    }
    #pragma unroll
    for (int o = 32; o; o >>= 1) { part1 += __shfl_xor(part1, o, 64); part3 += __shfl_xor(part3, o, 64); }
    __shared__ float r1[4], r3[4];
    int w = tid >> 6;
    if ((tid & 63) == 0) { r1[w] = part1; r3[w] = part3; }
    __syncthreads();
    float l1 = sqrtf((r1[0] + r1[1] + r1[2] + r1[3]) / 1072.f);
    float l3 = sqrtf((r3[0] + r3[1] + r3[2] + r3[3]) / 1024.f);
    for (int idx = tid; idx < 1024; idx += 256) {
        int b = idx >> 7, i = idx & 127;
        out[idx]        = semb[b * Ec + i];
        out[1024 + idx] = semb[b * Ec + 128 + i];
    }
    if (tid == 0) {
        out[2048] = 50.f * l1 + l3;
        out[2049] = l1;
        out[2050] = l3;
    }
    for (int idx = tid; idx < 1072; idx += 256) out[2051 + idx] = slog[idx];
}

extern "C" void kernel_launch(void* const* d_in, const int* in_sizes, int n_in,
                              void* d_out, int out_size, void* d_ws, size_t ws_size,
                              hipStream_t stream) {
    const float* X        = (const float*)d_in[0];
    const float* Yt       = (const float*)d_in[1];
    const float* wpe      = (const float*)d_in[2];
    const float* ln1_g    = (const float*)d_in[3];
    const float* ln1_b    = (const float*)d_in[4];
    const float* attn_w   = (const float*)d_in[5];
    const float* attn_b   = (const float*)d_in[6];
    const float* apw      = (const float*)d_in[7];
    const float* apb      = (const float*)d_in[8];
    const float* ln2_g    = (const float*)d_in[9];
    const float* ln2_b    = (const float*)d_in[10];
    const float* fcw      = (const float*)d_in[11];
    const float* fcb      = (const float*)d_in[12];
    const float* mpw      = (const float*)d_in[13];
    const float* mpb      = (const float*)d_in[14];
    const float* lnf_g    = (const float*)d_in[15];
    const float* lnf_b    = (const float*)d_in[16];
    const float* head_w   = (const float*)d_in[17];
    const float* head_b   = (const float*)d_in[18];

    char* ws = (char*)d_ws;
    const size_t MB = 1048576;
    __bf16* xres   = (__bf16*)(ws + 0 * MB);    // 8 MB
    __bf16* hb     = (__bf16*)(ws + 8 * MB);    // 8 MB; later Y3
    __bf16* Qb     = (__bf16*)(ws + 16 * MB);   // 8 MB
    __bf16* Kb     = (__bf16*)(ws + 24 * MB);   // 8 MB
    __bf16* Vb     = (__bf16*)(ws + 32 * MB);   // 8 MB; scratch -> Y4
    __bf16* Vt     = (__bf16*)(ws + 40 * MB);   // 8 MB
    __bf16* Y1     = (__bf16*)(ws + 48 * MB);   // 8 MB
    __bf16* Y2     = (__bf16*)(ws + 56 * MB);   // 8 MB
    __bf16* wb     = (__bf16*)(ws + 64 * MB);   // 1 MB
    float*  embsum = (float*)(ws + 65 * MB);    // 8 KB

    __bf16* Y3 = hb;     // hb dead after gemm_qkv
    __bf16* Y4 = Vb;     // Vb region free (V goes straight to Vt)

    __bf16* wqkv = wb;
    __bf16* wap  = wb + 196608;
    __bf16* wfc  = wb + 262144;
    __bf16* wmp  = wb + 393216;

    embed_prep_k<<<4096, 256, 0, stream>>>(X, wpe, ln1_g, ln1_b,
                                           attn_w, apw, fcw, mpw, wb, embsum, xres, hb);
    gemm_qkv<<<dim3(6, 128), 256, 0, stream>>>(hb, wqkv, attn_b, Qb, Kb, Vt);
    attn6_k<<<640, 512, 0, stream>>>(Qb, Kb, Vt, Y1, Y2, Y3, Y4);
    mega_k<<<256, 512, 0, stream>>>(Y1, Y2, Y3, Y4, wap, apb, xres, ln2_g, ln2_b,
                                    wfc, fcb, wmp, mpb, lnf_g, lnf_b, embsum);
    final_k<<<1, 256, 0, stream>>>(embsum, Yt, head_w, head_b, (float*)d_out);
}